// Round 15
// baseline (135.628 us; speedup 1.0000x reference)
//
#include <hip/hip_runtime.h>

typedef short short8 __attribute__((ext_vector_type(8)));
typedef short short4v __attribute__((ext_vector_type(4)));
typedef float f32x4 __attribute__((ext_vector_type(4)));
typedef float float4v __attribute__((ext_vector_type(4)));
typedef int int4v __attribute__((ext_vector_type(4)));
typedef int int2v __attribute__((ext_vector_type(2)));

__device__ __forceinline__ short f2bf(float f) {
  union { float f; unsigned u; } v; v.f = f;
  unsigned r = v.u + 0x7FFFu + ((v.u >> 16) & 1u);
  return (short)(r >> 16);
}

__device__ __forceinline__ unsigned cvtpk_bf16(float lo, float hi) {
  unsigned r;
  asm("v_cvt_pk_bf16_f32 %0, %1, %2" : "=v"(r) : "v"(lo), "v"(hi));
  return r;  // lo16 = bf16(lo), hi16 = bf16(hi)
}

// async global->LDS, 16B per lane; dest must be linear (wave base + lane*16)
#define GLD16(gp, lp)                                                   \
  __builtin_amdgcn_global_load_lds(                                     \
      (const __attribute__((address_space(1))) void*)(gp),              \
      (__attribute__((address_space(3))) void*)(lp), 16, 0, 0)

// Q scale: softmax uses exp2, so fold log2(e) into the 1/sqrt(64) scale
#define QSCALE 0.18033688011112042f

// ---------------- fused fp32 -> bf16 convert (x | w_qkv | w_proj) ----------------
__global__ __launch_bounds__(256) void cvt_all(
    const float* __restrict__ x, const float* __restrict__ wq, const float* __restrict__ wp,
    short* __restrict__ xb, short* __restrict__ wqb, short* __restrict__ wpb) {
  int i = blockIdx.x * 256 + threadIdx.x;  // in float4 units; total 2097152
  const float* s; short* d; int off;
  if (i < 1048576)      { s = x;  d = xb;  off = i; }
  else if (i < 1835008) { s = wq; d = wqb; off = i - 1048576; }
  else                  { s = wp; d = wpb; off = i - 1835008; }
  float4v v = ((const float4v*)s)[off];
  short4v o;
  o.x = f2bf(v.x); o.y = f2bf(v.y); o.z = f2bf(v.z); o.w = f2bf(v.w);
  ((short4v*)d)[off] = o;
}

// ---------------- GEMM: C[M,Ncols] = A[M,1024] @ Bw[Ncols,1024]^T + bias ----------------
// R14-proven: BK=32, 3 LDS slots (48KB -> 3 blocks/CU), depth-3 counted-vmcnt
// prefetch, XCD-affine flat-grid decode.
template <int MODE>
__global__ __launch_bounds__(256, 3) void gemm_bt(
    const short* __restrict__ A, const short* __restrict__ Bw,
    const float* __restrict__ bias,
    short* __restrict__ qo, short* __restrict__ ko, short* __restrict__ vto,
    float* __restrict__ outf) {
  __shared__ short As[3][128 * 32];  // 8KB per slot
  __shared__ short Bs[3][128 * 32];
  const int t = threadIdx.x;
  const int lane = t & 63, wid = t >> 6;
  const int g = lane >> 4, l15 = lane & 15;
  const int wr = (wid >> 1) * 64, wc = (wid & 1) * 64;
  // XCD-affine decode: bid = bn*32 + sub*8 + xcd -> bm = xcd*4 + sub
  const int bid = blockIdx.x;
  const int bm0 = ((bid & 7) * 4 + ((bid >> 3) & 3)) * 128;
  const int bn0 = (bid >> 5) * 128;

  const int sr = t >> 2;
  const int csrc = (t & 3) ^ ((t >> 3) & 3);

  const int gx = (g ^ ((l15 >> 1) & 3)) << 4;
  int aoff[4], boff[4];
#pragma unroll
  for (int f = 0; f < 4; ++f) {
    aoff[f] = (wr + f * 16 + l15) * 64 + gx;
    boff[f] = (wc + f * 16 + l15) * 64 + gx;
  }

  f32x4 acc[4][4] = {};

  auto stage = [&](int offB, int k0) {
#pragma unroll
    for (int i = 0; i < 2; ++i) {
      int row = i * 64 + sr;
      char* ldsA = (char*)&As[0][0] + offB + (i * 256 + (t & ~63)) * 16;
      char* ldsB = (char*)&Bs[0][0] + offB + (i * 256 + (t & ~63)) * 16;
      GLD16(A + (size_t)(bm0 + row) * 1024 + k0 + csrc * 8, ldsA);
      GLD16(Bw + (size_t)(bn0 + row) * 1024 + k0 + csrc * 8, ldsB);
    }
  };

  stage(0, 0);
  stage(8192, 32);
  stage(16384, 64);
  int off = 0;

  for (int it = 0; it < 32; ++it) {
    if (it < 30)       asm volatile("s_waitcnt vmcnt(8)" ::: "memory");
    else if (it == 30) asm volatile("s_waitcnt vmcnt(4)" ::: "memory");
    else               asm volatile("s_waitcnt vmcnt(0)" ::: "memory");
    __builtin_amdgcn_s_barrier();
    __builtin_amdgcn_sched_barrier(0);
    const char* AsB = (const char*)&As[0][0] + off;
    const char* BsB = (const char*)&Bs[0][0] + off;
    short8 a[4], b[4];
#pragma unroll
    for (int mi = 0; mi < 4; ++mi) a[mi] = *(const short8*)(AsB + aoff[mi]);
#pragma unroll
    for (int ni = 0; ni < 4; ++ni) b[ni] = *(const short8*)(BsB + boff[ni]);
#pragma unroll
    for (int mi = 0; mi < 4; ++mi)
#pragma unroll
      for (int ni = 0; ni < 4; ++ni)
        acc[mi][ni] = __builtin_amdgcn_mfma_f32_16x16x32_bf16(a[mi], b[ni], acc[mi][ni], 0, 0, 0);
    __builtin_amdgcn_sched_barrier(0);
    __builtin_amdgcn_s_barrier();
    __builtin_amdgcn_sched_barrier(0);
    if (it + 3 < 32) stage(off, (it + 3) * 32);
    off = (off == 16384) ? 0 : off + 8192;
  }

  if constexpr (MODE == 0) {
    const int which = bn0 >> 10;
    if (which == 2) {
#pragma unroll
      for (int mi = 0; mi < 4; ++mi) {
#pragma unroll
        for (int ni = 0; ni < 4; ++ni) {
          int gcol = bn0 + wc + ni * 16 + l15;
          int w1 = gcol & 1023;
          int h = w1 >> 6, dd = w1 & 63;
          float bv = bias[gcol];
          int grow0 = bm0 + wr + mi * 16 + g * 4;
          int b_ = grow0 >> 11, n0 = grow0 & 2047;
          int bh = b_ * 16 + h;
          int nl = n0 & 63;
          int np = (n0 & ~63) | (nl & 32) | ((nl & 12) << 1) | ((nl & 16) >> 2);
          int2v pk;
          pk.x = (int)cvtpk_bf16(acc[mi][ni][0] + bv, acc[mi][ni][1] + bv);
          pk.y = (int)cvtpk_bf16(acc[mi][ni][2] + bv, acc[mi][ni][3] + bv);
          *(int2v*)(vto + ((size_t)bh * 64 + dd) * 2048 + np) = pk;
        }
      }
    } else {
      short* dst = (which == 0) ? qo : ko;
      const float sc = (which == 0) ? QSCALE : 1.0f;
#pragma unroll
      for (int mi = 0; mi < 4; ++mi) {
#pragma unroll
        for (int ni = 0; ni < 4; ++ni) {
          int gcol = bn0 + wc + ni * 16 + l15;
          int w1 = gcol & 1023;
          int h = w1 >> 6, dd = w1 & 63;
          float bv = bias[gcol];
#pragma unroll
          for (int r = 0; r < 4; ++r) {
            int grow = bm0 + wr + mi * 16 + g * 4 + r;
            int b_ = grow >> 11, n = grow & 2047;
            int bh = b_ * 16 + h;
            dst[((size_t)bh * 2048 + n) * 64 + dd] = f2bf((acc[mi][ni][r] + bv) * sc);
          }
        }
      }
    }
  } else {
#pragma unroll
    for (int mi = 0; mi < 4; ++mi) {
#pragma unroll
      for (int ni = 0; ni < 4; ++ni) {
        int gcol = bn0 + wc + ni * 16 + l15;
        float bv = bias[gcol];
#pragma unroll
        for (int r = 0; r < 4; ++r) {
          int grow = bm0 + wr + mi * 16 + g * 4 + r;
          outf[(size_t)grow * 1024 + gcol] = acc[mi][ni][r] + bv;
        }
      }
    }
  }
}

// ---------------- flash attention: split-KV, 4 waves/SIMD ----------------
// 8 waves x 32 q-rows: wave = (qgroup qg = wid>>1, kvhalf hf = wid&1).
// Each (qg,hf) wave processes 16 KV tiles (its half of 2048), then the two
// halves merge (m,l,acc) through LDS. Doubles waves/SIMD to 4 at UNCHANGED
// DS- and VALU-per-work (R8's 2x-DS mistake avoided). Sync skeleton = R10's
// proven counted-vmcnt loop (4 GLD16/wave/phase, vmcnt(4) steady, stage(p+2)
// after the pinned second barrier). Waves 0-3 stage K, waves 4-7 stage V.
// Grid 512 x 512thr = 2 blocks/CU = 16 waves/CU. XCD-affine bh=bid&31.
__global__ __launch_bounds__(512, 4) void attn_fused(
    const short* __restrict__ Qg, const short* __restrict__ Kg,
    const short* __restrict__ Vtg, short* __restrict__ AO) {
  __shared__ char smem[65536];  // [K: 2 half x 2 buf x 8KB][V: same] ; reused for merge
#define KSB(hf, buf) (smem + ((hf) * 2 + (buf)) * 8192)
#define VSB(hf, buf) (smem + 32768 + ((hf) * 2 + (buf)) * 8192)
  const int bid = blockIdx.x;
  const int bh = bid & 31, qt = bid >> 5;
  const int t = threadIdx.x, wid = t >> 6, lane = t & 63;
  const int g = lane >> 4, l15 = lane & 15;
  const int qg = wid >> 1, hf = wid & 1;
  const int q0w = qt * 128 + qg * 32;
  const short* qb = Qg + ((size_t)bh * 2048 + q0w) * 64;
  const short* kb = Kg + (size_t)bh * 2048 * 64;
  const short* vb = Vtg + (size_t)bh * 64 * 2048;

  // staging geometry (256-thread groups): linear LDS dest, pre-swizzled src
  const int sr = (t & 255) >> 3;
  const int ssub = (t & 7) ^ ((t >> 3) & 7);
  const short* ksrc0 = kb + sr * 64 + ssub * 8;
  const short* vsrc0 = vb + (size_t)sr * 2048 + ssub * 8;

  // LICM: swizzled fragment offsets, shared by K and V reads
  const int swz = (l15 & 7) << 4;
  int foff[2][4];
#pragma unroll
  for (int kk = 0; kk < 2; ++kk)
#pragma unroll
    for (int f = 0; f < 4; ++f)
      foff[kk][f] = ((f * 16 + l15) * 128 + kk * 64 + g * 16) ^ swz;

  short8 bq[2][2];
#pragma unroll
  for (int qf = 0; qf < 2; ++qf)
#pragma unroll
    for (int kk = 0; kk < 2; ++kk)
      bq[qf][kk] = *(const short8*)(qb + (qf * 16 + l15) * 64 + kk * 32 + g * 8);

  // stage phase p: waves 0-3 stage K tiles (both halves), waves 4-7 stage V.
  // 4 GLD16 per wave per phase (uniform across waves -> FIFO invariant holds).
  auto stageP = [&](int buf, int p) {
    if (wid < 4) {
#pragma unroll
      for (int h2 = 0; h2 < 2; ++h2)
#pragma unroll
        for (int i = 0; i < 2; ++i)
          GLD16(ksrc0 + (size_t)(h2 * 1024 + p * 64 + i * 32) * 64,
                KSB(h2, buf) + i * 4096 + wid * 1024);
    } else {
#pragma unroll
      for (int h2 = 0; h2 < 2; ++h2)
#pragma unroll
        for (int i = 0; i < 2; ++i)
          GLD16(vsrc0 + (size_t)(i * 32) * 2048 + h2 * 1024 + p * 64,
                VSB(h2, buf) + i * 4096 + (wid - 4) * 1024);
    }
  };

  stageP(0, 0);  // 4 loads/wave
  stageP(1, 1);  // 8 in flight

  f32x4 acc[2][4] = {};
  float mrun[2] = {-3.0e38f, -3.0e38f}, lrun[2] = {0.f, 0.f};

  for (int p = 0; p < 16; ++p) {
    if (p == 15) asm volatile("s_waitcnt vmcnt(0)" ::: "memory");
    else         asm volatile("s_waitcnt vmcnt(4)" ::: "memory");
    __builtin_amdgcn_s_barrier();
    __builtin_amdgcn_sched_barrier(0);
    const char* KsB = (const char*)KSB(hf, p & 1);
    const char* VsB = (const char*)VSB(hf, p & 1);

    // S^T[kv][q]: s[qf][kf], kv = kf*16 + g*4 + r (within this half), q
    f32x4 s[2][4] = {};
#pragma unroll
    for (int kk = 0; kk < 2; ++kk) {
      short8 ak[4];
#pragma unroll
      for (int kf = 0; kf < 4; ++kf) ak[kf] = *(const short8*)(KsB + foff[kk][kf]);
#pragma unroll
      for (int kf = 0; kf < 4; ++kf)
#pragma unroll
        for (int qf = 0; qf < 2; ++qf)
          s[qf][kf] = __builtin_amdgcn_mfma_f32_16x16x32_bf16(ak[kf], bq[qf][kk], s[qf][kf], 0, 0, 0);
    }

    // tile max per qf
    float pm[2];
#pragma unroll
    for (int qf = 0; qf < 2; ++qf) {
      float m0 = fmaxf(s[qf][0][0], s[qf][0][1]);
      m0 = fmaxf(fmaxf(m0, s[qf][0][2]), s[qf][0][3]);
#pragma unroll
      for (int kf = 1; kf < 4; ++kf) {
        m0 = fmaxf(fmaxf(m0, s[qf][kf][0]), s[qf][kf][1]);
        m0 = fmaxf(fmaxf(m0, s[qf][kf][2]), s[qf][kf][3]);
      }
      float x = fmaxf(m0, __shfl_xor(m0, 16));
      pm[qf] = fmaxf(x, __shfl_xor(x, 32));
    }

    // defer-max (T13)
    if (!__all((pm[0] - mrun[0] <= 8.f) && (pm[1] - mrun[1] <= 8.f))) {
#pragma unroll
      for (int qf = 0; qf < 2; ++qf) {
        float mn = fmaxf(mrun[qf], pm[qf]);
        float alpha = __builtin_amdgcn_exp2f(mrun[qf] - mn);
        mrun[qf] = mn;
        lrun[qf] *= alpha;
#pragma unroll
        for (int df = 0; df < 4; ++df)
#pragma unroll
          for (int r = 0; r < 4; ++r) acc[qf][df][r] *= alpha;
      }
    }

    // P = exp2(S - m), row sums, pack to bf16 pairs (lane-local)
    unsigned wpk[2][4][2];
#pragma unroll
    for (int qf = 0; qf < 2; ++qf) {
      float rs = 0.f;
      float pp[4][4];
#pragma unroll
      for (int kf = 0; kf < 4; ++kf)
#pragma unroll
        for (int r = 0; r < 4; ++r) {
          pp[kf][r] = __builtin_amdgcn_exp2f(s[qf][kf][r] - mrun[qf]);
          rs += pp[kf][r];
        }
      rs += __shfl_xor(rs, 16);
      rs += __shfl_xor(rs, 32);
      lrun[qf] += rs;
#pragma unroll
      for (int kf = 0; kf < 4; ++kf)
#pragma unroll
        for (int h2 = 0; h2 < 2; ++h2)
          wpk[qf][kf][h2] = cvtpk_bf16(pp[kf][2 * h2], pp[kf][2 * h2 + 1]);
    }

    // O^T += V^T_perm @ P^T
#pragma unroll
    for (int kk = 0; kk < 2; ++kk) {
      short8 av[4];
#pragma unroll
      for (int df = 0; df < 4; ++df) av[df] = *(const short8*)(VsB + foff[kk][df]);
#pragma unroll
      for (int qf = 0; qf < 2; ++qf) {
        union { int4v i; short8 s; } pv;
        pv.i[0] = (int)wpk[qf][2 * kk][0];
        pv.i[1] = (int)wpk[qf][2 * kk][1];
        pv.i[2] = (int)wpk[qf][2 * kk + 1][0];
        pv.i[3] = (int)wpk[qf][2 * kk + 1][1];
#pragma unroll
        for (int df = 0; df < 4; ++df)
          acc[qf][df] = __builtin_amdgcn_mfma_f32_16x16x32_bf16(av[df], pv.s, acc[qf][df], 0, 0, 0);
      }
    }

    __builtin_amdgcn_sched_barrier(0);
    __builtin_amdgcn_s_barrier();
    __builtin_amdgcn_sched_barrier(0);
    if (p + 2 < 16) stageP(p & 1, p + 2);
  }

  // ---- merge the two KV halves through (reused) LDS ----
  // cacc: 4 qg x 64 lanes x 33 floats (stride-33: 2-way banks, free)
  float* cacc = (float*)smem;
  float* cml = (float*)(smem + 4 * 64 * 33 * 4);  // 4 qg x 64 lanes x 4
  __syncthreads();  // all tile reads done; LDS reusable
  if (hf == 1) {
    float* pa = cacc + (qg * 64 + lane) * 33;
#pragma unroll
    for (int qf = 0; qf < 2; ++qf)
#pragma unroll
      for (int df = 0; df < 4; ++df)
#pragma unroll
        for (int r = 0; r < 4; ++r) pa[qf * 16 + df * 4 + r] = acc[qf][df][r];
    float* pl = cml + (qg * 64 + lane) * 4;
    pl[0] = mrun[0]; pl[1] = lrun[0]; pl[2] = mrun[1]; pl[3] = lrun[1];
  }
  __syncthreads();
  if (hf == 0) {
    const float* pa = cacc + (qg * 64 + lane) * 33;
    const float* pl = cml + (qg * 64 + lane) * 4;
    const int b_ = bh >> 4, h = bh & 15;
#pragma unroll
    for (int qf = 0; qf < 2; ++qf) {
      float m1 = pl[qf * 2], l1 = pl[qf * 2 + 1];
      float M = fmaxf(mrun[qf], m1);
      float a0 = __builtin_amdgcn_exp2f(mrun[qf] - M);
      float a1 = __builtin_amdgcn_exp2f(m1 - M);
      float inv = 1.0f / (lrun[qf] * a0 + l1 * a1);
      short* outp = AO + ((size_t)b_ * 2048 + q0w + qf * 16 + l15) * 1024 + h * 64 + g * 4;
#pragma unroll
      for (int df = 0; df < 4; ++df) {
        short4v o;
#pragma unroll
        for (int r = 0; r < 4; ++r)
          o[r] = f2bf((acc[qf][df][r] * a0 + pa[qf * 16 + df * 4 + r] * a1) * inv);
        *(short4v*)(outp + df * 16) = o;
      }
    }
  }
#undef KSB
#undef VSB
}

// ---------------- launch ----------------
extern "C" void kernel_launch(void* const* d_in, const int* in_sizes, int n_in,
                              void* d_out, int out_size, void* d_ws, size_t ws_size,
                              hipStream_t stream) {
  const float* x = (const float*)d_in[0];
  const float* w_qkv = (const float*)d_in[1];
  const float* b_qkv = (const float*)d_in[2];
  const float* w_proj = (const float*)d_in[3];
  const float* b_proj = (const float*)d_in[4];
  float* out = (float*)d_out;
  char* ws = (char*)d_ws;

  short* xb    = (short*)(ws + (size_t)0);
  short* wqkvb = (short*)(ws + ((size_t)8 << 20));
  short* wprojb= (short*)(ws + ((size_t)14 << 20));
  short* qb    = (short*)(ws + ((size_t)16 << 20));
  short* kb    = (short*)(ws + ((size_t)24 << 20));
  short* vtb   = (short*)(ws + ((size_t)32 << 20));
  short* aob   = (short*)(ws + ((size_t)40 << 20));

  cvt_all<<<8192, 256, 0, stream>>>(x, w_qkv, w_proj, xb, wqkvb, wprojb);
  gemm_bt<0><<<768, 256, 0, stream>>>(xb, wqkvb, b_qkv, qb, kb, vtb, nullptr);
  attn_fused<<<512, 512, 0, stream>>>(qb, kb, vtb, aob);
  gemm_bt<1><<<256, 256, 0, stream>>>(aob, wprojb, b_proj, nullptr, nullptr, nullptr, out);
}

// Round 16
// 118.977 us; speedup vs baseline: 1.1399x; 1.1399x over previous
//
#include <hip/hip_runtime.h>

typedef short short8 __attribute__((ext_vector_type(8)));
typedef short short4v __attribute__((ext_vector_type(4)));
typedef float f32x4 __attribute__((ext_vector_type(4)));
typedef float float4v __attribute__((ext_vector_type(4)));
typedef int int4v __attribute__((ext_vector_type(4)));
typedef int int2v __attribute__((ext_vector_type(2)));

__device__ __forceinline__ short f2bf(float f) {
  union { float f; unsigned u; } v; v.f = f;
  unsigned r = v.u + 0x7FFFu + ((v.u >> 16) & 1u);
  return (short)(r >> 16);
}

__device__ __forceinline__ unsigned cvtpk_bf16(float lo, float hi) {
  unsigned r;
  asm("v_cvt_pk_bf16_f32 %0, %1, %2" : "=v"(r) : "v"(lo), "v"(hi));
  return r;  // lo16 = bf16(lo), hi16 = bf16(hi)
}

// async global->LDS, 16B per lane; dest must be linear (wave base + lane*16)
#define GLD16(gp, lp)                                                   \
  __builtin_amdgcn_global_load_lds(                                     \
      (const __attribute__((address_space(1))) void*)(gp),              \
      (__attribute__((address_space(3))) void*)(lp), 16, 0, 0)

// Q scale: softmax uses exp2, so fold log2(e) into the 1/sqrt(64) scale
#define QSCALE 0.18033688011112042f

// ---------------- fused fp32 -> bf16 convert (x | w_qkv | w_proj) ----------------
__global__ __launch_bounds__(256) void cvt_all(
    const float* __restrict__ x, const float* __restrict__ wq, const float* __restrict__ wp,
    short* __restrict__ xb, short* __restrict__ wqb, short* __restrict__ wpb) {
  int i = blockIdx.x * 256 + threadIdx.x;  // in float4 units; total 2097152
  const float* s; short* d; int off;
  if (i < 1048576)      { s = x;  d = xb;  off = i; }
  else if (i < 1835008) { s = wq; d = wqb; off = i - 1048576; }
  else                  { s = wp; d = wpb; off = i - 1835008; }
  float4v v = ((const float4v*)s)[off];
  short4v o;
  o.x = f2bf(v.x); o.y = f2bf(v.y); o.z = f2bf(v.z); o.w = f2bf(v.w);
  ((short4v*)d)[off] = o;
}

// ---------------- GEMM: C[M,Ncols] = A[M,1024] @ Bw[Ncols,1024]^T + bias ----------------
// R14-proven: BK=32, 3 LDS slots (48KB -> 3 blocks/CU), depth-3 counted-vmcnt
// prefetch, XCD-affine flat-grid decode.
template <int MODE>
__global__ __launch_bounds__(256, 3) void gemm_bt(
    const short* __restrict__ A, const short* __restrict__ Bw,
    const float* __restrict__ bias,
    short* __restrict__ qo, short* __restrict__ ko, short* __restrict__ vto,
    float* __restrict__ outf) {
  __shared__ short As[3][128 * 32];  // 8KB per slot
  __shared__ short Bs[3][128 * 32];
  const int t = threadIdx.x;
  const int lane = t & 63, wid = t >> 6;
  const int g = lane >> 4, l15 = lane & 15;
  const int wr = (wid >> 1) * 64, wc = (wid & 1) * 64;
  // XCD-affine decode: bid = bn*32 + sub*8 + xcd -> bm = xcd*4 + sub
  const int bid = blockIdx.x;
  const int bm0 = ((bid & 7) * 4 + ((bid >> 3) & 3)) * 128;
  const int bn0 = (bid >> 5) * 128;

  const int sr = t >> 2;
  const int csrc = (t & 3) ^ ((t >> 3) & 3);

  const int gx = (g ^ ((l15 >> 1) & 3)) << 4;
  int aoff[4], boff[4];
#pragma unroll
  for (int f = 0; f < 4; ++f) {
    aoff[f] = (wr + f * 16 + l15) * 64 + gx;
    boff[f] = (wc + f * 16 + l15) * 64 + gx;
  }

  f32x4 acc[4][4] = {};

  auto stage = [&](int offB, int k0) {
#pragma unroll
    for (int i = 0; i < 2; ++i) {
      int row = i * 64 + sr;
      char* ldsA = (char*)&As[0][0] + offB + (i * 256 + (t & ~63)) * 16;
      char* ldsB = (char*)&Bs[0][0] + offB + (i * 256 + (t & ~63)) * 16;
      GLD16(A + (size_t)(bm0 + row) * 1024 + k0 + csrc * 8, ldsA);
      GLD16(Bw + (size_t)(bn0 + row) * 1024 + k0 + csrc * 8, ldsB);
    }
  };

  stage(0, 0);
  stage(8192, 32);
  stage(16384, 64);
  int off = 0;

  for (int it = 0; it < 32; ++it) {
    if (it < 30)       asm volatile("s_waitcnt vmcnt(8)" ::: "memory");
    else if (it == 30) asm volatile("s_waitcnt vmcnt(4)" ::: "memory");
    else               asm volatile("s_waitcnt vmcnt(0)" ::: "memory");
    __builtin_amdgcn_s_barrier();
    __builtin_amdgcn_sched_barrier(0);
    const char* AsB = (const char*)&As[0][0] + off;
    const char* BsB = (const char*)&Bs[0][0] + off;
    short8 a[4], b[4];
#pragma unroll
    for (int mi = 0; mi < 4; ++mi) a[mi] = *(const short8*)(AsB + aoff[mi]);
#pragma unroll
    for (int ni = 0; ni < 4; ++ni) b[ni] = *(const short8*)(BsB + boff[ni]);
#pragma unroll
    for (int mi = 0; mi < 4; ++mi)
#pragma unroll
      for (int ni = 0; ni < 4; ++ni)
        acc[mi][ni] = __builtin_amdgcn_mfma_f32_16x16x32_bf16(a[mi], b[ni], acc[mi][ni], 0, 0, 0);
    __builtin_amdgcn_sched_barrier(0);
    __builtin_amdgcn_s_barrier();
    __builtin_amdgcn_sched_barrier(0);
    if (it + 3 < 32) stage(off, (it + 3) * 32);
    off = (off == 16384) ? 0 : off + 8192;
  }

  if constexpr (MODE == 0) {
    const int which = bn0 >> 10;
    if (which == 2) {
#pragma unroll
      for (int mi = 0; mi < 4; ++mi) {
#pragma unroll
        for (int ni = 0; ni < 4; ++ni) {
          int gcol = bn0 + wc + ni * 16 + l15;
          int w1 = gcol & 1023;
          int h = w1 >> 6, dd = w1 & 63;
          float bv = bias[gcol];
          int grow0 = bm0 + wr + mi * 16 + g * 4;
          int b_ = grow0 >> 11, n0 = grow0 & 2047;
          int bh = b_ * 16 + h;
          int nl = n0 & 63;
          int np = (n0 & ~63) | (nl & 32) | ((nl & 12) << 1) | ((nl & 16) >> 2);
          int2v pk;
          pk.x = (int)cvtpk_bf16(acc[mi][ni][0] + bv, acc[mi][ni][1] + bv);
          pk.y = (int)cvtpk_bf16(acc[mi][ni][2] + bv, acc[mi][ni][3] + bv);
          *(int2v*)(vto + ((size_t)bh * 64 + dd) * 2048 + np) = pk;
        }
      }
    } else {
      short* dst = (which == 0) ? qo : ko;
      const float sc = (which == 0) ? QSCALE : 1.0f;
#pragma unroll
      for (int mi = 0; mi < 4; ++mi) {
#pragma unroll
        for (int ni = 0; ni < 4; ++ni) {
          int gcol = bn0 + wc + ni * 16 + l15;
          int w1 = gcol & 1023;
          int h = w1 >> 6, dd = w1 & 63;
          float bv = bias[gcol];
#pragma unroll
          for (int r = 0; r < 4; ++r) {
            int grow = bm0 + wr + mi * 16 + g * 4 + r;
            int b_ = grow >> 11, n = grow & 2047;
            int bh = b_ * 16 + h;
            dst[((size_t)bh * 2048 + n) * 64 + dd] = f2bf((acc[mi][ni][r] + bv) * sc);
          }
        }
      }
    }
  } else {
#pragma unroll
    for (int mi = 0; mi < 4; ++mi) {
#pragma unroll
      for (int ni = 0; ni < 4; ++ni) {
        int gcol = bn0 + wc + ni * 16 + l15;
        float bv = bias[gcol];
#pragma unroll
        for (int r = 0; r < 4; ++r) {
          int grow = bm0 + wr + mi * 16 + g * 4 + r;
          outf[(size_t)grow * 1024 + gcol] = acc[mi][ni][r] + bv;
        }
      }
    }
  }
}

// ---------------- flash attention: split-KV, 4 waves/SIMD ----------------
// R15 structure with the launch-bounds spill fixed: (512,4) capped VGPR at 64
// (8 waves/SIMD budget) -> acc spilled to scratch (WRITE_SIZE 36MB, 82us).
// (512,2) => 2 blocks/CU, 4 waves/SIMD, 128-VGPR cap: body needs ~100, fits.
// 8 waves x 32 q-rows: wave = (qgroup qg = wid>>1, kvhalf hf = wid&1); each
// wave does 16 KV tiles (half of 2048); halves merge (m,l,acc) via LDS.
// DS- and VALU-per-work unchanged vs R10; waves/SIMD doubled 2 -> 4.
__global__ __launch_bounds__(512, 2) void attn_fused(
    const short* __restrict__ Qg, const short* __restrict__ Kg,
    const short* __restrict__ Vtg, short* __restrict__ AO) {
  __shared__ char smem[65536];  // [K: 2 half x 2 buf x 8KB][V: same]; reused for merge
#define KSB(hf, buf) (smem + ((hf) * 2 + (buf)) * 8192)
#define VSB(hf, buf) (smem + 32768 + ((hf) * 2 + (buf)) * 8192)
  const int bid = blockIdx.x;
  const int bh = bid & 31, qt = bid >> 5;
  const int t = threadIdx.x, wid = t >> 6, lane = t & 63;
  const int g = lane >> 4, l15 = lane & 15;
  const int qg = wid >> 1, hf = wid & 1;
  const int q0w = qt * 128 + qg * 32;
  const short* qb = Qg + ((size_t)bh * 2048 + q0w) * 64;
  const short* kb = Kg + (size_t)bh * 2048 * 64;
  const short* vb = Vtg + (size_t)bh * 64 * 2048;

  // staging geometry (256-thread groups): linear LDS dest, pre-swizzled src
  const int sr = (t & 255) >> 3;
  const int ssub = (t & 7) ^ ((t >> 3) & 7);
  const short* ksrc0 = kb + sr * 64 + ssub * 8;
  const short* vsrc0 = vb + (size_t)sr * 2048 + ssub * 8;

  // LICM: swizzled fragment offsets, shared by K and V reads
  const int swz = (l15 & 7) << 4;
  int foff[2][4];
#pragma unroll
  for (int kk = 0; kk < 2; ++kk)
#pragma unroll
    for (int f = 0; f < 4; ++f)
      foff[kk][f] = ((f * 16 + l15) * 128 + kk * 64 + g * 16) ^ swz;

  short8 bq[2][2];
#pragma unroll
  for (int qf = 0; qf < 2; ++qf)
#pragma unroll
    for (int kk = 0; kk < 2; ++kk)
      bq[qf][kk] = *(const short8*)(qb + (qf * 16 + l15) * 64 + kk * 32 + g * 8);

  // stage phase p: waves 0-3 stage K tiles (both halves), waves 4-7 stage V.
  // 4 GLD16 per wave per phase (uniform across waves -> FIFO invariant holds).
  auto stageP = [&](int buf, int p) {
    if (wid < 4) {
#pragma unroll
      for (int h2 = 0; h2 < 2; ++h2)
#pragma unroll
        for (int i = 0; i < 2; ++i)
          GLD16(ksrc0 + (size_t)(h2 * 1024 + p * 64 + i * 32) * 64,
                KSB(h2, buf) + i * 4096 + wid * 1024);
    } else {
#pragma unroll
      for (int h2 = 0; h2 < 2; ++h2)
#pragma unroll
        for (int i = 0; i < 2; ++i)
          GLD16(vsrc0 + (size_t)(i * 32) * 2048 + h2 * 1024 + p * 64,
                VSB(h2, buf) + i * 4096 + (wid - 4) * 1024);
    }
  };

  stageP(0, 0);  // 4 loads/wave
  stageP(1, 1);  // 8 in flight

  f32x4 acc[2][4] = {};
  float mrun[2] = {-3.0e38f, -3.0e38f}, lrun[2] = {0.f, 0.f};

  for (int p = 0; p < 16; ++p) {
    if (p == 15) asm volatile("s_waitcnt vmcnt(0)" ::: "memory");
    else         asm volatile("s_waitcnt vmcnt(4)" ::: "memory");
    __builtin_amdgcn_s_barrier();
    __builtin_amdgcn_sched_barrier(0);
    const char* KsB = (const char*)KSB(hf, p & 1);
    const char* VsB = (const char*)VSB(hf, p & 1);

    // S^T[kv][q]: s[qf][kf], kv = kf*16 + g*4 + r (within this half), q
    f32x4 s[2][4] = {};
#pragma unroll
    for (int kk = 0; kk < 2; ++kk) {
      short8 ak[4];
#pragma unroll
      for (int kf = 0; kf < 4; ++kf) ak[kf] = *(const short8*)(KsB + foff[kk][kf]);
#pragma unroll
      for (int kf = 0; kf < 4; ++kf)
#pragma unroll
        for (int qf = 0; qf < 2; ++qf)
          s[qf][kf] = __builtin_amdgcn_mfma_f32_16x16x32_bf16(ak[kf], bq[qf][kk], s[qf][kf], 0, 0, 0);
    }

    // tile max per qf
    float pm[2];
#pragma unroll
    for (int qf = 0; qf < 2; ++qf) {
      float m0 = fmaxf(s[qf][0][0], s[qf][0][1]);
      m0 = fmaxf(fmaxf(m0, s[qf][0][2]), s[qf][0][3]);
#pragma unroll
      for (int kf = 1; kf < 4; ++kf) {
        m0 = fmaxf(fmaxf(m0, s[qf][kf][0]), s[qf][kf][1]);
        m0 = fmaxf(fmaxf(m0, s[qf][kf][2]), s[qf][kf][3]);
      }
      float x = fmaxf(m0, __shfl_xor(m0, 16));
      pm[qf] = fmaxf(x, __shfl_xor(x, 32));
    }

    // defer-max (T13)
    if (!__all((pm[0] - mrun[0] <= 8.f) && (pm[1] - mrun[1] <= 8.f))) {
#pragma unroll
      for (int qf = 0; qf < 2; ++qf) {
        float mn = fmaxf(mrun[qf], pm[qf]);
        float alpha = __builtin_amdgcn_exp2f(mrun[qf] - mn);
        mrun[qf] = mn;
        lrun[qf] *= alpha;
#pragma unroll
        for (int df = 0; df < 4; ++df)
#pragma unroll
          for (int r = 0; r < 4; ++r) acc[qf][df][r] *= alpha;
      }
    }

    // P = exp2(S - m), row sums, pack to bf16 pairs (lane-local)
    unsigned wpk[2][4][2];
#pragma unroll
    for (int qf = 0; qf < 2; ++qf) {
      float rs = 0.f;
      float pp[4][4];
#pragma unroll
      for (int kf = 0; kf < 4; ++kf)
#pragma unroll
        for (int r = 0; r < 4; ++r) {
          pp[kf][r] = __builtin_amdgcn_exp2f(s[qf][kf][r] - mrun[qf]);
          rs += pp[kf][r];
        }
      rs += __shfl_xor(rs, 16);
      rs += __shfl_xor(rs, 32);
      lrun[qf] += rs;
#pragma unroll
      for (int kf = 0; kf < 4; ++kf)
#pragma unroll
        for (int h2 = 0; h2 < 2; ++h2)
          wpk[qf][kf][h2] = cvtpk_bf16(pp[kf][2 * h2], pp[kf][2 * h2 + 1]);
    }

    // O^T += V^T_perm @ P^T
#pragma unroll
    for (int kk = 0; kk < 2; ++kk) {
      short8 av[4];
#pragma unroll
      for (int df = 0; df < 4; ++df) av[df] = *(const short8*)(VsB + foff[kk][df]);
#pragma unroll
      for (int qf = 0; qf < 2; ++qf) {
        union { int4v i; short8 s; } pv;
        pv.i[0] = (int)wpk[qf][2 * kk][0];
        pv.i[1] = (int)wpk[qf][2 * kk][1];
        pv.i[2] = (int)wpk[qf][2 * kk + 1][0];
        pv.i[3] = (int)wpk[qf][2 * kk + 1][1];
#pragma unroll
        for (int df = 0; df < 4; ++df)
          acc[qf][df] = __builtin_amdgcn_mfma_f32_16x16x32_bf16(av[df], pv.s, acc[qf][df], 0, 0, 0);
      }
    }

    __builtin_amdgcn_sched_barrier(0);
    __builtin_amdgcn_s_barrier();
    __builtin_amdgcn_sched_barrier(0);
    if (p + 2 < 16) stageP(p & 1, p + 2);
  }

  // ---- merge the two KV halves through (reused) LDS ----
  // cacc: 4 qg x 64 lanes x 33 floats (stride-33: 2-way banks, free)
  float* cacc = (float*)smem;
  float* cml = (float*)(smem + 4 * 64 * 33 * 4);  // 4 qg x 64 lanes x 4
  __syncthreads();  // all tile reads done; LDS reusable
  if (hf == 1) {
    float* pa = cacc + (qg * 64 + lane) * 33;
#pragma unroll
    for (int qf = 0; qf < 2; ++qf)
#pragma unroll
      for (int df = 0; df < 4; ++df)
#pragma unroll
        for (int r = 0; r < 4; ++r) pa[qf * 16 + df * 4 + r] = acc[qf][df][r];
    float* pl = cml + (qg * 64 + lane) * 4;
    pl[0] = mrun[0]; pl[1] = lrun[0]; pl[2] = mrun[1]; pl[3] = lrun[1];
  }
  __syncthreads();
  if (hf == 0) {
    const float* pa = cacc + (qg * 64 + lane) * 33;
    const float* pl = cml + (qg * 64 + lane) * 4;
    const int b_ = bh >> 4, h = bh & 15;
#pragma unroll
    for (int qf = 0; qf < 2; ++qf) {
      float m1 = pl[qf * 2], l1 = pl[qf * 2 + 1];
      float M = fmaxf(mrun[qf], m1);
      float a0 = __builtin_amdgcn_exp2f(mrun[qf] - M);
      float a1 = __builtin_amdgcn_exp2f(m1 - M);
      float inv = 1.0f / (lrun[qf] * a0 + l1 * a1);
      short* outp = AO + ((size_t)b_ * 2048 + q0w + qf * 16 + l15) * 1024 + h * 64 + g * 4;
#pragma unroll
      for (int df = 0; df < 4; ++df) {
        short4v o;
#pragma unroll
        for (int r = 0; r < 4; ++r)
          o[r] = f2bf((acc[qf][df][r] * a0 + pa[qf * 16 + df * 4 + r] * a1) * inv);
        *(short4v*)(outp + df * 16) = o;
      }
    }
  }
#undef KSB
#undef VSB
}

// ---------------- launch ----------------
extern "C" void kernel_launch(void* const* d_in, const int* in_sizes, int n_in,
                              void* d_out, int out_size, void* d_ws, size_t ws_size,
                              hipStream_t stream) {
  const float* x = (const float*)d_in[0];
  const float* w_qkv = (const float*)d_in[1];
  const float* b_qkv = (const float*)d_in[2];
  const float* w_proj = (const float*)d_in[3];
  const float* b_proj = (const float*)d_in[4];
  float* out = (float*)d_out;
  char* ws = (char*)d_ws;

  short* xb    = (short*)(ws + (size_t)0);
  short* wqkvb = (short*)(ws + ((size_t)8 << 20));
  short* wprojb= (short*)(ws + ((size_t)14 << 20));
  short* qb    = (short*)(ws + ((size_t)16 << 20));
  short* kb    = (short*)(ws + ((size_t)24 << 20));
  short* vtb   = (short*)(ws + ((size_t)32 << 20));
  short* aob   = (short*)(ws + ((size_t)40 << 20));

  cvt_all<<<8192, 256, 0, stream>>>(x, w_qkv, w_proj, xb, wqkvb, wprojb);
  gemm_bt<0><<<768, 256, 0, stream>>>(xb, wqkvb, b_qkv, qb, kb, vtb, nullptr);
  attn_fused<<<512, 512, 0, stream>>>(qb, kb, vtb, aob);
  gemm_bt<1><<<256, 256, 0, stream>>>(aob, wprojb, b_proj, nullptr, nullptr, nullptr, out);
}

// Round 17
// 115.509 us; speedup vs baseline: 1.1742x; 1.0300x over previous
//
#include <hip/hip_runtime.h>

typedef short short8 __attribute__((ext_vector_type(8)));
typedef short short4v __attribute__((ext_vector_type(4)));
typedef float f32x4 __attribute__((ext_vector_type(4)));
typedef float float4v __attribute__((ext_vector_type(4)));
typedef int int4v __attribute__((ext_vector_type(4)));
typedef int int2v __attribute__((ext_vector_type(2)));

__device__ __forceinline__ short f2bf(float f) {
  union { float f; unsigned u; } v; v.f = f;
  unsigned r = v.u + 0x7FFFu + ((v.u >> 16) & 1u);
  return (short)(r >> 16);
}

__device__ __forceinline__ unsigned cvtpk_bf16(float lo, float hi) {
  unsigned r;
  asm("v_cvt_pk_bf16_f32 %0, %1, %2" : "=v"(r) : "v"(lo), "v"(hi));
  return r;  // lo16 = bf16(lo), hi16 = bf16(hi)
}

// async global->LDS, 16B per lane; dest must be linear (wave base + lane*16)
#define GLD16(gp, lp)                                                   \
  __builtin_amdgcn_global_load_lds(                                     \
      (const __attribute__((address_space(1))) void*)(gp),              \
      (__attribute__((address_space(3))) void*)(lp), 16, 0, 0)

// Q scale: softmax uses exp2, so fold log2(e) into the 1/sqrt(64) scale
#define QSCALE 0.18033688011112042f

// ---------------- fused fp32 -> bf16 convert (x | w_qkv | w_proj) ----------------
__global__ __launch_bounds__(256) void cvt_all(
    const float* __restrict__ x, const float* __restrict__ wq, const float* __restrict__ wp,
    short* __restrict__ xb, short* __restrict__ wqb, short* __restrict__ wpb) {
  int i = blockIdx.x * 256 + threadIdx.x;  // in float4 units; total 2097152
  const float* s; short* d; int off;
  if (i < 1048576)      { s = x;  d = xb;  off = i; }
  else if (i < 1835008) { s = wq; d = wqb; off = i - 1048576; }
  else                  { s = wp; d = wpb; off = i - 1835008; }
  float4v v = ((const float4v*)s)[off];
  short4v o;
  o.x = f2bf(v.x); o.y = f2bf(v.y); o.z = f2bf(v.z); o.w = f2bf(v.w);
  ((short4v*)d)[off] = o;
}

// ---------------- qkv GEMM: 256x256 tile, 4-phase/K-tile counted-vmcnt ----------------
// C[4096,3072] = A[4096,1024] @ Bw[3072,1024]^T + bias -> scatter Q/K/V^T.
// 8 waves (2M x 4N), per-wave 128x64 out (acc[8][4]). BK=64, 16 K-tiles.
// LDS 128KB: 2 bufs x {A: 2x(128x64), B: 2x(128x64)} halves of 16KB.
// Pipeline: buf = k&1. Phase mp of K-tile k: (1) issue 2 stage-loads of
// half-tile mp of k+1 into buf^1; (2) mp==0: vmcnt(2) [k's 8 oldest landed,
// 2 newest stay in flight - never drains] + barrier; (3) B-frags cached in
// regs at mp==0 (8 b128), A-frags per phase (4 b128), 16 MFMA (setprio);
// (4) trailing barrier at mp==3 only (separates buf-k reads from k+1's
// stage into buf-k). k==15: vmcnt(0), no stage. Grid 192 (16 bm x 12 bn),
// XCD-affine: bm-pair per XCD (A-panels 512KB L2-resident).
__global__ __launch_bounds__(512, 2) void gemm256(
    const short* __restrict__ A, const short* __restrict__ Bw,
    const float* __restrict__ bias,
    short* __restrict__ qo, short* __restrict__ ko, short* __restrict__ vto) {
  __shared__ char lds[131072];
  const int t = threadIdx.x;
  const int lane = t & 63, wid = t >> 6;
  const int g = lane >> 4, l15 = lane & 15;
  const int wr = wid >> 2, wc = wid & 3;
  const int bid = blockIdx.x;
  // bijective: xcd = bid&7 -> bm = xcd*2 + bit3, bn = bid>>4
  const int bm0 = ((bid & 7) * 2 + ((bid >> 3) & 1)) * 256;
  const int bn0 = (bid >> 4) * 256;

  // staging: linear LDS dest, pre-swizzled source (proven 128B-row swizzle)
  const int srow = t >> 3;
  const int ssub = (t & 7) ^ ((t >> 3) & 7);

  // fragment in-row offsets: (kk*64 + g*16) ^ ((l15&7)<<4), stays in 128B row
  const int swz = (l15 & 7) << 4;
  int inrow[2];
  inrow[0] = (g * 16) ^ swz;
  inrow[1] = (64 + g * 16) ^ swz;
  const int bRow0 = (wc & 1) * 64;  // B rows within its half

  f32x4 acc[8][4] = {};

  // stage half-tile ht (0:Ah0 1:Ah1 2:Bh0 3:Bh1) of K-tile kt into buf b
  auto stageHT = [&](int b, int kt, int ht) {
    const int isB = ht >> 1, hh = ht & 1;
    const short* mat = isB ? Bw : A;
    const int base = isB ? bn0 : bm0;
    const short* src = mat + (size_t)(base + hh * 128 + srow) * 1024 + kt * 64 + ssub * 8;
    char* dst = lds + b * 65536 + isB * 32768 + hh * 16384 + t * 16;
    GLD16(src, dst);                    // rows 0-63 of the half
    GLD16(src + 64 * 1024, dst + 8192); // rows 64-127
  };

  // prologue: K-tile 0's 4 half-tiles (8 loads, FIFO order = ht 0..3)
#pragma unroll
  for (int ht = 0; ht < 4; ++ht) stageHT(0, 0, ht);

  for (int k = 0; k < 16; ++k) {
    const int buf = k & 1;
    const char* Ab = lds + buf * 65536 + wr * 16384;
    const char* Bb = lds + buf * 65536 + 32768 + (wc >> 1) * 16384;
    short8 bB[4][2];
#pragma unroll
    for (int mp = 0; mp < 4; ++mp) {
      if (k + 1 < 16) stageHT(buf ^ 1, k + 1, mp);  // 2 loads, newest in FIFO
      __builtin_amdgcn_sched_barrier(0);
      if (mp == 0) {
        if (k + 1 < 16) asm volatile("s_waitcnt vmcnt(2)" ::: "memory");
        else            asm volatile("s_waitcnt vmcnt(0)" ::: "memory");
        __builtin_amdgcn_s_barrier();   // K-tile k fully staged, all waves
        __builtin_amdgcn_sched_barrier(0);
#pragma unroll
        for (int n = 0; n < 4; ++n)
#pragma unroll
          for (int kk = 0; kk < 2; ++kk)
            bB[n][kk] = *(const short8*)(Bb + (bRow0 + n * 16 + l15) * 128 + inrow[kk]);
      }
      short8 aA[2][2];
#pragma unroll
      for (int mm = 0; mm < 2; ++mm)
#pragma unroll
        for (int kk = 0; kk < 2; ++kk)
          aA[mm][kk] = *(const short8*)(Ab + ((mp * 2 + mm) * 16 + l15) * 128 + inrow[kk]);
      __builtin_amdgcn_s_setprio(1);
#pragma unroll
      for (int mm = 0; mm < 2; ++mm)
#pragma unroll
        for (int n = 0; n < 4; ++n)
#pragma unroll
          for (int kk = 0; kk < 2; ++kk)
            acc[mp * 2 + mm][n] = __builtin_amdgcn_mfma_f32_16x16x32_bf16(
                aA[mm][kk], bB[n][kk], acc[mp * 2 + mm][n], 0, 0, 0);
      __builtin_amdgcn_s_setprio(0);
      if (mp == 3) {
        __builtin_amdgcn_sched_barrier(0);
        __builtin_amdgcn_s_barrier();   // all waves done reading buf k
        __builtin_amdgcn_sched_barrier(0);
      }
    }
  }

  // epilogue: scatter Q (scaled), K, V^T(bit-permuted) — which is block-uniform
  const int which = bn0 >> 10;
  if (which == 2) {
#pragma unroll
    for (int m = 0; m < 8; ++m) {
#pragma unroll
      for (int n = 0; n < 4; ++n) {
        int gcol = bn0 + wc * 64 + n * 16 + l15;
        int w1 = gcol & 1023;
        int h = w1 >> 6, dd = w1 & 63;
        float bv = bias[gcol];
        int grow0 = bm0 + wr * 128 + m * 16 + g * 4;
        int b_ = grow0 >> 11, n0 = grow0 & 2047;
        int bh = b_ * 16 + h;
        int nl = n0 & 63;
        // kv bit-perm [b5][b3][b2][b4][b1][b0]; n0 4-aligned -> np too
        int np = (n0 & ~63) | (nl & 32) | ((nl & 12) << 1) | ((nl & 16) >> 2);
        int2v pk;
        pk.x = (int)cvtpk_bf16(acc[m][n][0] + bv, acc[m][n][1] + bv);
        pk.y = (int)cvtpk_bf16(acc[m][n][2] + bv, acc[m][n][3] + bv);
        *(int2v*)(vto + ((size_t)bh * 64 + dd) * 2048 + np) = pk;
      }
    }
  } else {
    short* dst = (which == 0) ? qo : ko;
    const float sc = (which == 0) ? QSCALE : 1.0f;
#pragma unroll
    for (int m = 0; m < 8; ++m) {
#pragma unroll
      for (int n = 0; n < 4; ++n) {
        int gcol = bn0 + wc * 64 + n * 16 + l15;
        int w1 = gcol & 1023;
        int h = w1 >> 6, dd = w1 & 63;
        float bv = bias[gcol];
#pragma unroll
        for (int r = 0; r < 4; ++r) {
          int grow = bm0 + wr * 128 + m * 16 + g * 4 + r;
          int b_ = grow >> 11, n2 = grow & 2047;
          int bh = b_ * 16 + h;
          dst[((size_t)bh * 2048 + n2) * 64 + dd] = f2bf((acc[m][n][r] + bv) * sc);
        }
      }
    }
  }
}

// ---------------- proj GEMM (R14-proven): BK=32, 3 slots, depth-3 vmcnt ----------------
__global__ __launch_bounds__(256, 3) void gemm_proj(
    const short* __restrict__ A, const short* __restrict__ Bw,
    const float* __restrict__ bias, float* __restrict__ outf) {
  __shared__ short As[3][128 * 32];
  __shared__ short Bs[3][128 * 32];
  const int t = threadIdx.x;
  const int lane = t & 63, wid = t >> 6;
  const int g = lane >> 4, l15 = lane & 15;
  const int wr = (wid >> 1) * 64, wc = (wid & 1) * 64;
  const int bid = blockIdx.x;
  const int bm0 = ((bid & 7) * 4 + ((bid >> 3) & 3)) * 128;
  const int bn0 = (bid >> 5) * 128;

  const int sr = t >> 2;
  const int csrc = (t & 3) ^ ((t >> 3) & 3);

  const int gx = (g ^ ((l15 >> 1) & 3)) << 4;
  int aoff[4], boff[4];
#pragma unroll
  for (int f = 0; f < 4; ++f) {
    aoff[f] = (wr + f * 16 + l15) * 64 + gx;
    boff[f] = (wc + f * 16 + l15) * 64 + gx;
  }

  f32x4 acc[4][4] = {};

  auto stage = [&](int offB, int k0) {
#pragma unroll
    for (int i = 0; i < 2; ++i) {
      int row = i * 64 + sr;
      char* ldsA = (char*)&As[0][0] + offB + (i * 256 + (t & ~63)) * 16;
      char* ldsB = (char*)&Bs[0][0] + offB + (i * 256 + (t & ~63)) * 16;
      GLD16(A + (size_t)(bm0 + row) * 1024 + k0 + csrc * 8, ldsA);
      GLD16(Bw + (size_t)(bn0 + row) * 1024 + k0 + csrc * 8, ldsB);
    }
  };

  stage(0, 0);
  stage(8192, 32);
  stage(16384, 64);
  int off = 0;

  for (int it = 0; it < 32; ++it) {
    if (it < 30)       asm volatile("s_waitcnt vmcnt(8)" ::: "memory");
    else if (it == 30) asm volatile("s_waitcnt vmcnt(4)" ::: "memory");
    else               asm volatile("s_waitcnt vmcnt(0)" ::: "memory");
    __builtin_amdgcn_s_barrier();
    __builtin_amdgcn_sched_barrier(0);
    const char* AsB = (const char*)&As[0][0] + off;
    const char* BsB = (const char*)&Bs[0][0] + off;
    short8 a[4], b[4];
#pragma unroll
    for (int mi = 0; mi < 4; ++mi) a[mi] = *(const short8*)(AsB + aoff[mi]);
#pragma unroll
    for (int ni = 0; ni < 4; ++ni) b[ni] = *(const short8*)(BsB + boff[ni]);
#pragma unroll
    for (int mi = 0; mi < 4; ++mi)
#pragma unroll
      for (int ni = 0; ni < 4; ++ni)
        acc[mi][ni] = __builtin_amdgcn_mfma_f32_16x16x32_bf16(a[mi], b[ni], acc[mi][ni], 0, 0, 0);
    __builtin_amdgcn_sched_barrier(0);
    __builtin_amdgcn_s_barrier();
    __builtin_amdgcn_sched_barrier(0);
    if (it + 3 < 32) stage(off, (it + 3) * 32);
    off = (off == 16384) ? 0 : off + 8192;
  }

#pragma unroll
  for (int mi = 0; mi < 4; ++mi) {
#pragma unroll
    for (int ni = 0; ni < 4; ++ni) {
      int gcol = bn0 + wc + ni * 16 + l15;
      float bv = bias[gcol];
#pragma unroll
      for (int r = 0; r < 4; ++r) {
        int grow = bm0 + wr + mi * 16 + g * 4 + r;
        outf[(size_t)grow * 1024 + gcol] = acc[mi][ni][r] + bv;
      }
    }
  }
}

// ---------------- flash attention (R10-proven, 58.7us — attn floor) ----------------
// 4 waves x 32 q-rows, grid 512, 2 blocks/CU, XCD-affine bh=bid&31, 2
// sub-tiles per counted-vmcnt phase. Abandoned (do not retry): R8
// 16-rows/wave, R11 deferred pipeline (NaN), R12 setprio (null), R13
// barrier-free (93us), R15/R16 split-KV (62us).
__global__ __launch_bounds__(256, 2) void attn_fused(
    const short* __restrict__ Qg, const short* __restrict__ Kg,
    const short* __restrict__ Vtg, short* __restrict__ AO) {
  __shared__ short Ks[4][64 * 64];  // slot = buf*2 + sub, 8KB each
  __shared__ short Vs[4][64 * 64];
  const int bid = blockIdx.x;
  const int bh = bid & 31, qt = bid >> 5;
  const int t = threadIdx.x, wid = t >> 6, lane = t & 63;
  const int g = lane >> 4, l15 = lane & 15;
  const int q0w = qt * 128 + wid * 32;
  const short* qb = Qg + ((size_t)bh * 2048 + q0w) * 64;
  const short* kb = Kg + (size_t)bh * 2048 * 64;
  const short* vb = Vtg + (size_t)bh * 64 * 2048;

  const int srow = t >> 3;
  const int ssub = (t & 7) ^ (srow & 7);
  const short* ksrc0 = kb + srow * 64 + ssub * 8;
  const short* vsrc0 = vb + (size_t)srow * 2048 + ssub * 8;

  const int swz = (l15 & 7) << 4;
  int foff[2][4];
#pragma unroll
  for (int kk = 0; kk < 2; ++kk)
#pragma unroll
    for (int f = 0; f < 4; ++f)
      foff[kk][f] = ((f * 16 + l15) * 128 + kk * 64 + g * 16) ^ swz;

  short8 bq[2][2];
#pragma unroll
  for (int qf = 0; qf < 2; ++qf)
#pragma unroll
    for (int kk = 0; kk < 2; ++kk)
      bq[qf][kk] = *(const short8*)(qb + (qf * 16 + l15) * 64 + kk * 32 + g * 8);

  auto stageP = [&](int buf, int p) {
    const int n0 = p * 128;
#pragma unroll
    for (int sub = 0; sub < 2; ++sub) {
      const int nn = n0 + sub * 64;
      char* ldsK = (char*)&Ks[buf * 2 + sub][0] + wid * 1024;
      char* ldsV = (char*)&Vs[buf * 2 + sub][0] + wid * 1024;
#pragma unroll
      for (int i = 0; i < 2; ++i) {
        GLD16(ksrc0 + (size_t)(nn + i * 32) * 64, ldsK + i * 4096);
        GLD16(vsrc0 + (size_t)i * 32 * 2048 + nn, ldsV + i * 4096);
      }
    }
  };

  stageP(0, 0);
  stageP(1, 1);

  f32x4 acc[2][4] = {};
  float mrun[2] = {-3.0e38f, -3.0e38f}, lrun[2] = {0.f, 0.f};

  for (int p = 0; p < 16; ++p) {
    if (p == 15) asm volatile("s_waitcnt vmcnt(0)" ::: "memory");
    else         asm volatile("s_waitcnt vmcnt(8)" ::: "memory");
    __builtin_amdgcn_s_barrier();
    __builtin_amdgcn_sched_barrier(0);
    const int buf = p & 1;

#pragma unroll
    for (int sub = 0; sub < 2; ++sub) {
      const char* KsB = (const char*)&Ks[buf * 2 + sub][0];
      const char* VsB = (const char*)&Vs[buf * 2 + sub][0];

      f32x4 s[2][4] = {};
#pragma unroll
      for (int kk = 0; kk < 2; ++kk) {
        short8 ak[4];
#pragma unroll
        for (int kf = 0; kf < 4; ++kf) ak[kf] = *(const short8*)(KsB + foff[kk][kf]);
#pragma unroll
        for (int kf = 0; kf < 4; ++kf)
#pragma unroll
          for (int qf = 0; qf < 2; ++qf)
            s[qf][kf] = __builtin_amdgcn_mfma_f32_16x16x32_bf16(ak[kf], bq[qf][kk], s[qf][kf], 0, 0, 0);
      }

      float pm[2];
#pragma unroll
      for (int qf = 0; qf < 2; ++qf) {
        float m0 = fmaxf(s[qf][0][0], s[qf][0][1]);
        m0 = fmaxf(fmaxf(m0, s[qf][0][2]), s[qf][0][3]);
#pragma unroll
        for (int kf = 1; kf < 4; ++kf) {
          m0 = fmaxf(fmaxf(m0, s[qf][kf][0]), s[qf][kf][1]);
          m0 = fmaxf(fmaxf(m0, s[qf][kf][2]), s[qf][kf][3]);
        }
        float x = fmaxf(m0, __shfl_xor(m0, 16));
        pm[qf] = fmaxf(x, __shfl_xor(x, 32));
      }

      if (!__all((pm[0] - mrun[0] <= 8.f) && (pm[1] - mrun[1] <= 8.f))) {
#pragma unroll
        for (int qf = 0; qf < 2; ++qf) {
          float mn = fmaxf(mrun[qf], pm[qf]);
          float alpha = __builtin_amdgcn_exp2f(mrun[qf] - mn);
          mrun[qf] = mn;
          lrun[qf] *= alpha;
#pragma unroll
          for (int df = 0; df < 4; ++df)
#pragma unroll
            for (int r = 0; r < 4; ++r) acc[qf][df][r] *= alpha;
        }
      }

      unsigned wpk[2][4][2];
#pragma unroll
      for (int qf = 0; qf < 2; ++qf) {
        float rs = 0.f;
        float pp[4][4];
#pragma unroll
        for (int kf = 0; kf < 4; ++kf)
#pragma unroll
          for (int r = 0; r < 4; ++r) {
            pp[kf][r] = __builtin_amdgcn_exp2f(s[qf][kf][r] - mrun[qf]);
            rs += pp[kf][r];
          }
        rs += __shfl_xor(rs, 16);
        rs += __shfl_xor(rs, 32);
        lrun[qf] += rs;
#pragma unroll
        for (int kf = 0; kf < 4; ++kf)
#pragma unroll
          for (int h = 0; h < 2; ++h)
            wpk[qf][kf][h] = cvtpk_bf16(pp[kf][2 * h], pp[kf][2 * h + 1]);
      }

#pragma unroll
      for (int kk = 0; kk < 2; ++kk) {
        short8 av[4];
#pragma unroll
        for (int df = 0; df < 4; ++df) av[df] = *(const short8*)(VsB + foff[kk][df]);
#pragma unroll
        for (int qf = 0; qf < 2; ++qf) {
          union { int4v i; short8 s; } pv;
          pv.i[0] = (int)wpk[qf][2 * kk][0];
          pv.i[1] = (int)wpk[qf][2 * kk][1];
          pv.i[2] = (int)wpk[qf][2 * kk + 1][0];
          pv.i[3] = (int)wpk[qf][2 * kk + 1][1];
#pragma unroll
          for (int df = 0; df < 4; ++df)
            acc[qf][df] = __builtin_amdgcn_mfma_f32_16x16x32_bf16(av[df], pv.s, acc[qf][df], 0, 0, 0);
        }
      }
    }

    __builtin_amdgcn_sched_barrier(0);
    __builtin_amdgcn_s_barrier();
    __builtin_amdgcn_sched_barrier(0);
    if (p + 2 < 16) stageP(buf, p + 2);
  }

  const int b_ = bh >> 4, h = bh & 15;
#pragma unroll
  for (int qf = 0; qf < 2; ++qf) {
    const float inv = 1.0f / lrun[qf];
    short* outp = AO + ((size_t)b_ * 2048 + q0w + qf * 16 + l15) * 1024 + h * 64 + g * 4;
#pragma unroll
    for (int df = 0; df < 4; ++df) {
      short4v o;
#pragma unroll
      for (int r = 0; r < 4; ++r) o[r] = f2bf(acc[qf][df][r] * inv);
      *(short4v*)(outp + df * 16) = o;
    }
  }
}

// ---------------- launch ----------------
extern "C" void kernel_launch(void* const* d_in, const int* in_sizes, int n_in,
                              void* d_out, int out_size, void* d_ws, size_t ws_size,
                              hipStream_t stream) {
  const float* x = (const float*)d_in[0];
  const float* w_qkv = (const float*)d_in[1];
  const float* b_qkv = (const float*)d_in[2];
  const float* w_proj = (const float*)d_in[3];
  const float* b_proj = (const float*)d_in[4];
  float* out = (float*)d_out;
  char* ws = (char*)d_ws;

  short* xb    = (short*)(ws + (size_t)0);
  short* wqkvb = (short*)(ws + ((size_t)8 << 20));
  short* wprojb= (short*)(ws + ((size_t)14 << 20));
  short* qb    = (short*)(ws + ((size_t)16 << 20));
  short* kb    = (short*)(ws + ((size_t)24 << 20));
  short* vtb   = (short*)(ws + ((size_t)32 << 20));
  short* aob   = (short*)(ws + ((size_t)40 << 20));

  cvt_all<<<8192, 256, 0, stream>>>(x, w_qkv, w_proj, xb, wqkvb, wprojb);
  gemm256<<<192, 512, 0, stream>>>(xb, wqkvb, b_qkv, qb, kb, vtb);
  attn_fused<<<512, 256, 0, stream>>>(qb, kb, vtb, aob);
  gemm_proj<<<256, 256, 0, stream>>>(aob, wprojb, b_proj, out);
}